// Round 1
// baseline (351.232 us; speedup 1.0000x reference)
//
#include <hip/hip_runtime.h>
#include <math.h>

// Problem constants (from reference): B=64, S=4096, H=256.
namespace {
constexpr int kB = 64;
constexpr int kS = 4096;
constexpr int kH = 256;
constexpr int kChunks = 32;                           // chunks per batch row
constexpr int kChunkS = kS / kChunks;                 // 128 positions per block
constexpr int kWavesPerBlock = 4;                     // 256 threads
constexpr int kPosPerWave = kChunkS / kWavesPerBlock; // 32 positions per wave
constexpr int kPartStride = kH + 2;                   // acc[256] + m + l
constexpr float kLog2e = 1.4426950408889634f;
}

// 6-step DPP reduction; total sum lands in lane 63. Chains are dependent
// WITHIN one value but independent ACROSS values -> call on 8 values for ILP.
__device__ __forceinline__ float dpp_red64(float x) {
  float f = x;
#define DPP_STEP(ctrl)                                                     \
  f += __int_as_float(__builtin_amdgcn_update_dpp(                         \
      0, __float_as_int(f), ctrl, 0xF, 0xF, true))
  DPP_STEP(0x111);  // row_shr:1
  DPP_STEP(0x112);  // row_shr:2
  DPP_STEP(0x114);  // row_shr:4
  DPP_STEP(0x118);  // row_shr:8
  DPP_STEP(0x142);  // row_bcast:15
  DPP_STEP(0x143);  // row_bcast:31
#undef DPP_STEP
  return f;
}

__device__ __forceinline__ float rdl63(float f) {
  return __int_as_float(__builtin_amdgcn_readlane(__float_as_int(f), 63));
}

__device__ __forceinline__ float dot4(const float4 a, const float4 b) {
  return fmaf(a.x, b.x, fmaf(a.y, b.y, fmaf(a.z, b.z, a.w * b.w)));
}

// ---- batched valid-position extraction -------------------------------------
// rem is a wave-uniform 32-bit mask of valid positions (scalar regs).
// Each TAKE_SLOT pulls the next set bit and issues the (uniform-guarded)
// 1 KB row load. Invalid slots get zero rows so 0*garbage can never pollute
// the accumulator (0*NaN = NaN hazard).
#define TAKE_SLOT(X, i)                                                      \
  const bool X##v##i = (rem != 0u);                                          \
  const int X##s##i = __ffs(rem) - 1; /* -1 when empty; never dereferenced */\
  rem &= (rem - 1u);                                                         \
  float4 X##x##i;                                                            \
  if (X##v##i) {                                                             \
    X##x##i = *reinterpret_cast<const float4*>(xw + (size_t)X##s##i * kH);   \
  } else {                                                                   \
    X##x##i = make_float4(0.f, 0.f, 0.f, 0.f);                               \
  }

#define TAKE8(X)                                                             \
  TAKE_SLOT(X, 0) TAKE_SLOT(X, 1) TAKE_SLOT(X, 2) TAKE_SLOT(X, 3)            \
  TAKE_SLOT(X, 4) TAKE_SLOT(X, 5) TAKE_SLOT(X, 6) TAKE_SLOT(X, 7)

// Tree-shaped accumulator update: depth ~4 instead of an 9-deep fma chain.
#define ACC_COMP(X, comp, dst)                                               \
  {                                                                          \
    const float u0 = fmaf(w1, X##x1.comp, w0 * X##x0.comp);                  \
    const float u1 = fmaf(w3, X##x3.comp, w2 * X##x2.comp);                  \
    const float u2 = fmaf(w5, X##x5.comp, w4 * X##x4.comp);                  \
    const float u3 = fmaf(w7, X##x7.comp, w6 * X##x6.comp);                  \
    dst = fmaf(dst, alpha, (u0 + u1) + (u2 + u3));                           \
  }

// Process one batch of (up to) 8 positions: 8 independent dot+reduce chains,
// then ONE online-softmax update. Slot-valid flags are wave-uniform, so all
// the ?: selects are cheap scalar-driven cndmasks; the outer if is a uniform
// s_cbranch (skips empty tail batches entirely).
#define PROCESS8(X)                                                          \
  if (X##v0) {                                                               \
    const float p0 = dpp_red64(dot4(X##x0, q4));                             \
    const float p1 = dpp_red64(dot4(X##x1, q4));                             \
    const float p2 = dpp_red64(dot4(X##x2, q4));                             \
    const float p3 = dpp_red64(dot4(X##x3, q4));                             \
    const float p4 = dpp_red64(dot4(X##x4, q4));                             \
    const float p5 = dpp_red64(dot4(X##x5, q4));                             \
    const float p6 = dpp_red64(dot4(X##x6, q4));                             \
    const float p7 = dpp_red64(dot4(X##x7, q4));                             \
    const float s0 = rdl63(p0) * kLog2e;                                     \
    const float s1 = rdl63(p1) * kLog2e;                                     \
    const float s2 = rdl63(p2) * kLog2e;                                     \
    const float s3 = rdl63(p3) * kLog2e;                                     \
    const float s4 = rdl63(p4) * kLog2e;                                     \
    const float s5 = rdl63(p5) * kLog2e;                                     \
    const float s6 = rdl63(p6) * kLog2e;                                     \
    const float s7 = rdl63(p7) * kLog2e;                                     \
    const float e0 = X##v0 ? s0 : -INFINITY;                                 \
    const float e1 = X##v1 ? s1 : -INFINITY;                                 \
    const float e2 = X##v2 ? s2 : -INFINITY;                                 \
    const float e3 = X##v3 ? s3 : -INFINITY;                                 \
    const float e4 = X##v4 ? s4 : -INFINITY;                                 \
    const float e5 = X##v5 ? s5 : -INFINITY;                                 \
    const float e6 = X##v6 ? s6 : -INFINITY;                                 \
    const float e7 = X##v7 ? s7 : -INFINITY;                                 \
    const float m8 = fmaxf(fmaxf(fmaxf(e0, e1), fmaxf(e2, e3)),             \
                           fmaxf(fmaxf(e4, e5), fmaxf(e6, e7)));            \
    const float m_new = fmaxf(m, m8);                                        \
    const float alpha = __builtin_amdgcn_exp2f(m - m_new); /* exp2(-inf)=0 */\
    const float w0 = X##v0 ? __builtin_amdgcn_exp2f(s0 - m_new) : 0.f;       \
    const float w1 = X##v1 ? __builtin_amdgcn_exp2f(s1 - m_new) : 0.f;       \
    const float w2 = X##v2 ? __builtin_amdgcn_exp2f(s2 - m_new) : 0.f;       \
    const float w3 = X##v3 ? __builtin_amdgcn_exp2f(s3 - m_new) : 0.f;       \
    const float w4 = X##v4 ? __builtin_amdgcn_exp2f(s4 - m_new) : 0.f;       \
    const float w5 = X##v5 ? __builtin_amdgcn_exp2f(s5 - m_new) : 0.f;       \
    const float w6 = X##v6 ? __builtin_amdgcn_exp2f(s6 - m_new) : 0.f;       \
    const float w7 = X##v7 ? __builtin_amdgcn_exp2f(s7 - m_new) : 0.f;       \
    l = fmaf(l, alpha, ((w0 + w1) + (w2 + w3)) + ((w4 + w5) + (w6 + w7)));   \
    ACC_COMP(X, x, ax)                                                       \
    ACC_COMP(X, y, ay)                                                       \
    ACC_COMP(X, z, az)                                                       \
    ACC_COMP(X, w, aw)                                                       \
    m = m_new;                                                               \
  }

// Pass 1: flash-style online softmax-weighted sum over a chunk of S.
// mask values are exactly {0,1}; mask==0 rows have softmax weight exactly 0
// in fp32, so we SKIP them (halves HBM traffic, bit-equivalent). vs the
// previous version: positions are processed in BATCHES OF 8 with one batch
// of loads prefetched ahead, so the 6-step DPP reduce chains run at ILP=8
// and the loop-carried online-softmax update is amortized 8x.
// launch_bounds(256,4): 128-VGPR cap — two 8-row batches (64 VGPRs) fit
// without scratch spills (the previous (256,8)=64-VGPR cap was spill-prone).
__global__ __launch_bounds__(256, 4) void pass1_kernel(
    const float* __restrict__ x, const float* __restrict__ mask,
    const float* __restrict__ q, float* __restrict__ part) {
  const int blk = blockIdx.x;
  const int b = blk >> 5;  // blk / kChunks
  const int c = blk & (kChunks - 1);
  const int tid = threadIdx.x;
  const int wave = tid >> 6;
  const int lane = tid & 63;

  const float4 q4 = *reinterpret_cast<const float4*>(q + b * kH + lane * 4);
  const int s_base = c * kChunkS + wave * kPosPerWave;
  const float* xw = x + ((size_t)b * kS + s_base) * kH + lane * 4;
  const float* mrow = mask + b * kS + s_base;

  // Wave-uniform bitmask of valid positions (bit i = mask[s_base+i] != 0).
  const float mv = mrow[lane & 31];
  unsigned int rem = (unsigned int)(__ballot(mv != 0.f) & 0xffffffffull);

  float m = -INFINITY;  // running max in base-2 units
  float l = 0.f;
  float ax = 0.f, ay = 0.f, az = 0.f, aw = 0.f;

  // 32 positions = at most 4 batches; fully unrolled ping-pong so the next
  // batch's 8 KB of loads are always in flight during the current compute.
  // Peak row liveness is 2 batches (A dead before C's take completes, etc).
  TAKE8(A)
  TAKE8(B)
  PROCESS8(A)
  TAKE8(C)
  PROCESS8(B)
  TAKE8(D)
  PROCESS8(C)
  PROCESS8(D)

  // Combine the block's 4 waves in LDS (base-2 exponents).
  __shared__ float sm[kWavesPerBlock];
  __shared__ float sl[kWavesPerBlock];
  __shared__ float sacc[kWavesPerBlock][kH];
  if (lane == 0) { sm[wave] = m; sl[wave] = l; }
  *reinterpret_cast<float4*>(&sacc[wave][lane * 4]) =
      make_float4(ax, ay, az, aw);
  __syncthreads();

  const float m_b = fmaxf(fmaxf(sm[0], sm[1]), fmaxf(sm[2], sm[3]));
  // Guard: if the whole chunk is masked, m_b=-inf; use 0 in the exponent
  // differences so a_i = exp2(-inf - 0) = 0 (avoids (-inf)-(-inf)=NaN).
  const float m_bs = (m_b == -INFINITY) ? 0.f : m_b;
  const float a0 = __builtin_amdgcn_exp2f(sm[0] - m_bs);
  const float a1 = __builtin_amdgcn_exp2f(sm[1] - m_bs);
  const float a2 = __builtin_amdgcn_exp2f(sm[2] - m_bs);
  const float a3 = __builtin_amdgcn_exp2f(sm[3] - m_bs);
  float* out = part + (size_t)blk * kPartStride;
  out[tid] = sacc[0][tid] * a0 + sacc[1][tid] * a1 +
             sacc[2][tid] * a2 + sacc[3][tid] * a3;
  if (tid == 0) {
    out[kH] = m_b;  // -inf for fully-masked chunk -> scale 0 in pass 2
    out[kH + 1] = sl[0] * a0 + sl[1] * a1 + sl[2] * a2 + sl[3] * a3;
  }
}

// Pass 2: per-batch combine of 32 partials + fused 512->256 linear epilogue.
__global__ __launch_bounds__(256, 4) void pass2_kernel(
    const float* __restrict__ part, const float* __restrict__ q,
    const float* __restrict__ W, const float* __restrict__ bias,
    float* __restrict__ out) {
  const int b = blockIdx.x;
  const int tid = threadIdx.x;

  const float* pb = part + (size_t)b * kChunks * kPartStride;
  float m_g = -INFINITY;  // finite: every row has >=1 valid position
  #pragma unroll
  for (int c = 0; c < kChunks; ++c)
    m_g = fmaxf(m_g, pb[c * kPartStride + kH]);
  float l_g = 0.f, num = 0.f;
  #pragma unroll 4
  for (int c = 0; c < kChunks; ++c) {
    const float* p = pb + c * kPartStride;
    const float scale = __builtin_amdgcn_exp2f(p[kH] - m_g);
    l_g += scale * p[kH + 1];
    num += scale * p[tid];  // coalesced across the 256 threads
  }
  const float msg = num / l_g;
  out[(size_t)b * kH + tid] = msg;  // output 0: extracted_msg

  __shared__ float conc[2 * kH];
  conc[tid] = q[b * kH + tid];
  conc[kH + tid] = msg;
  __syncthreads();

  float acc = bias[tid];
  const float* wr = W + (size_t)tid * (2 * kH);  // row h = tid of W [H, 2H]
  #pragma unroll 8
  for (int j = 0; j < 2 * kH; j += 4) {
    const float4 w4 = *reinterpret_cast<const float4*>(wr + j);
    acc += conc[j] * w4.x + conc[j + 1] * w4.y +
           conc[j + 2] * w4.z + conc[j + 3] * w4.w;
  }
  out[(size_t)(kB * kH) + (size_t)b * kH + tid] = acc;  // output 1: control_emb
}

extern "C" void kernel_launch(void* const* d_in, const int* in_sizes, int n_in,
                              void* d_out, int out_size, void* d_ws, size_t ws_size,
                              hipStream_t stream) {
  const float* x    = (const float*)d_in[0];  // inp_seq [B,S,H]
  const float* mask = (const float*)d_in[1];  // [B,S]
  const float* q    = (const float*)d_in[2];  // [B,H]
  const float* W    = (const float*)d_in[3];  // [H,2H]
  const float* bias = (const float*)d_in[4];  // [H]
  float* out = (float*)d_out;                 // [B*H extracted_msg][B*H control_emb]
  float* part = (float*)d_ws;                 // B*kChunks*(H+2) floats = 2.1 MB

  pass1_kernel<<<kB * kChunks, 256, 0, stream>>>(x, mask, q, part);
  pass2_kernel<<<kB, 256, 0, stream>>>(part, q, W, bias, out);
}